// Round 5
// baseline (954.893 us; speedup 1.0000x reference)
//
#include <hip/hip_runtime.h>

#define IN_F 256
#define OUT_F 64
#define SORT_CHUNK 16384
#define BKT_SHIFT 7
#define BKT_NODES 128
#define MAX_NB 1024

typedef __attribute__((ext_vector_type(8))) short short8;
typedef __attribute__((ext_vector_type(4))) float f32x4;

static __device__ __forceinline__ short f2bf(float f) {
    union { float f; unsigned u; } v; v.f = f;
    unsigned r = v.u + 0x7FFFu + ((v.u >> 16) & 1u);  // RNE
    return (short)(r >> 16);
}
static __device__ __forceinline__ float bf2f(short s) {
    return __int_as_float(((unsigned)(unsigned short)s) << 16);
}

// ---------------- prep: Wt[n][k] = bf16(W[k][n]) ----------------
__global__ __launch_bounds__(256)
void prep_w_kernel(const float* __restrict__ W, short* __restrict__ Wt) {
    int i = blockIdx.x * 256 + threadIdx.x;
    if (i < IN_F * OUT_F) {
        int k = i / OUT_F, n = i % OUT_F;
        Wt[n * IN_F + k] = f2bf(W[i]);
    }
}

// ---------------- fc: h(bf16) = x @ W + b via MFMA ----------------
__global__ __launch_bounds__(256, 4)
void fc_mfma_kernel(const float* __restrict__ x, const short* __restrict__ Wt,
                    const float* __restrict__ b, short* __restrict__ h, int nRows) {
    __shared__ short Wl[OUT_F * IN_F];  // 32 KB, swizzled
    {
        const uint4* src = (const uint4*)Wt;  // 2048 16B slots
        #pragma unroll
        for (int it = 0; it < 8; ++it) {
            int g = it * 256 + threadIdx.x;
            int n = g >> 5, s = g & 31;
            *(uint4*)((char*)Wl + n * 512 + (s ^ (n & 7)) * 16) = src[g];
        }
    }
    __syncthreads();

    const int wv = threadIdx.x >> 6;
    const int l  = threadIdx.x & 63;
    const int lr = l & 15;
    const int kg = l >> 4;

    const int rowbase = (blockIdx.x * 4 + wv) * 32;
    if (rowbase >= nRows) return;

    const int ar0 = min(rowbase + lr,      nRows - 1);
    const int ar1 = min(rowbase + 16 + lr, nRows - 1);
    const float* xp0 = x + (size_t)ar0 * IN_F + kg * 8;
    const float* xp1 = x + (size_t)ar1 * IN_F + kg * 8;

    f32x4 acc[2][4];
    #pragma unroll
    for (int m = 0; m < 2; ++m)
        #pragma unroll
        for (int n = 0; n < 4; ++n) acc[m][n] = (f32x4)0.f;

    #pragma unroll
    for (int kt = 0; kt < 8; ++kt) {
        const int K0 = kt * 32;
        float4 a0lo = *(const float4*)(xp0 + K0);
        float4 a0hi = *(const float4*)(xp0 + K0 + 4);
        float4 a1lo = *(const float4*)(xp1 + K0);
        float4 a1hi = *(const float4*)(xp1 + K0 + 4);

        short8 a0, a1;
        a0[0] = f2bf(a0lo.x); a0[1] = f2bf(a0lo.y);
        a0[2] = f2bf(a0lo.z); a0[3] = f2bf(a0lo.w);
        a0[4] = f2bf(a0hi.x); a0[5] = f2bf(a0hi.y);
        a0[6] = f2bf(a0hi.z); a0[7] = f2bf(a0hi.w);
        a1[0] = f2bf(a1lo.x); a1[1] = f2bf(a1lo.y);
        a1[2] = f2bf(a1lo.z); a1[3] = f2bf(a1lo.w);
        a1[4] = f2bf(a1hi.x); a1[5] = f2bf(a1hi.y);
        a1[6] = f2bf(a1hi.z); a1[7] = f2bf(a1hi.w);

        short8 bf[4];
        #pragma unroll
        for (int nt = 0; nt < 4; ++nt) {
            const int col = nt * 16 + lr;
            const int slot = (kt * 4 + kg) ^ (col & 7);
            bf[nt] = *(const short8*)((const char*)Wl + col * 512 + slot * 16);
        }
        #pragma unroll
        for (int nt = 0; nt < 4; ++nt) {
            acc[0][nt] = __builtin_amdgcn_mfma_f32_16x16x32_bf16(a0, bf[nt], acc[0][nt], 0, 0, 0);
            acc[1][nt] = __builtin_amdgcn_mfma_f32_16x16x32_bf16(a1, bf[nt], acc[1][nt], 0, 0, 0);
        }
    }

    #pragma unroll
    for (int m = 0; m < 2; ++m) {
        #pragma unroll
        for (int nt = 0; nt < 4; ++nt) {
            const int col = nt * 16 + lr;
            const float bias = b[col];
            #pragma unroll
            for (int j = 0; j < 4; ++j) {
                const int r = rowbase + m * 16 + kg * 4 + j;
                if (r < nRows)
                    h[(size_t)r * OUT_F + col] = f2bf(acc[m][nt][j] + bias);
            }
        }
    }
}

// ---------------- bucket counting sort ----------------
// pass A: per-(bucket, block) histogram. No global atomics.
__global__ __launch_bounds__(256)
void bhist_kernel(const int* __restrict__ dst, int* __restrict__ counts,
                  int nE, int NB, int nSB) {
    __shared__ int lh[MAX_NB];
    for (int b = threadIdx.x; b < NB; b += 256) lh[b] = 0;
    __syncthreads();
    int base = blockIdx.x * SORT_CHUNK;
    int lim = min(nE, base + SORT_CHUNK);
    for (int e = base + threadIdx.x; e < lim; e += 256)
        atomicAdd(&lh[dst[e] >> BKT_SHIFT], 1);
    __syncthreads();
    for (int b = threadIdx.x; b < NB; b += 256)
        counts[b * nSB + blockIdx.x] = lh[b];
}

// exclusive scan over n = NB*nSB elements (3-pass)
__global__ __launch_bounds__(256)
void scan1_kernel(const int* __restrict__ cnt, int* __restrict__ off,
                  int* __restrict__ part, int n) {
    __shared__ int sh[256];
    int base = blockIdx.x * 1024;
    int t = threadIdx.x;
    int v[4]; int s = 0;
    #pragma unroll
    for (int i = 0; i < 4; ++i) {
        int idx = base + t * 4 + i;
        v[i] = (idx < n) ? cnt[idx] : 0;
        s += v[i];
    }
    sh[t] = s;
    __syncthreads();
    for (int d = 1; d < 256; d <<= 1) {
        int val = (t >= d) ? sh[t - d] : 0;
        __syncthreads();
        sh[t] += val;
        __syncthreads();
    }
    if (t == 255) part[blockIdx.x] = sh[255];
    int run = (t == 0) ? 0 : sh[t - 1];
    #pragma unroll
    for (int i = 0; i < 4; ++i) {
        int idx = base + t * 4 + i;
        if (idx < n) off[idx] = run;
        run += v[i];
    }
}

__global__ __launch_bounds__(128)
void scan2_kernel(int* __restrict__ part, int nPart) {
    __shared__ int sh[128];
    int t = threadIdx.x;
    sh[t] = (t < nPart) ? part[t] : 0;
    __syncthreads();
    for (int d = 1; d < 128; d <<= 1) {
        int val = (t >= d) ? sh[t - d] : 0;
        __syncthreads();
        sh[t] += val;
        __syncthreads();
    }
    if (t < nPart) part[t] = (t == 0) ? 0 : sh[t - 1];
}

__global__ __launch_bounds__(256)
void scan3_kernel(int* __restrict__ off, const int* __restrict__ part, int n) {
    for (int i = blockIdx.x * blockDim.x + threadIdx.x; i < n;
         i += gridDim.x * blockDim.x)
        off[i] += part[i >> 10];
}

// pass B: stable scatter into bucket order. pack = (src | dstlow<<17, w)
__global__ __launch_bounds__(256)
void bfill_kernel(const int* __restrict__ src, const int* __restrict__ dst,
                  const float* __restrict__ w, const int* __restrict__ bases,
                  int2* __restrict__ pack, int nE, int NB, int nSB) {
    __shared__ int cur[MAX_NB];
    for (int b = threadIdx.x; b < NB; b += 256)
        cur[b] = bases[b * nSB + blockIdx.x];
    __syncthreads();
    int base = blockIdx.x * SORT_CHUNK;
    int lim = min(nE, base + SORT_CHUNK);
    for (int e = base + threadIdx.x; e < lim; e += 256) {
        int d = dst[e];
        int p = atomicAdd(&cur[d >> BKT_SHIFT], 1);
        pack[p] = make_int2(src[e] | ((d & (BKT_NODES - 1)) << 17),
                            __float_as_int(w[e]));
    }
}

// ---------------- bgather: one block per bucket, LDS fp32 accumulator ----
__global__ __launch_bounds__(256)
void bgather_kernel(const short* __restrict__ h, const int* __restrict__ bases,
                    const int2* __restrict__ pack, float* __restrict__ out,
                    int nRows, int nE, int NB, int nSB) {
    __shared__ float acc[BKT_NODES * OUT_F];  // 32 KB
    const int b = blockIdx.x;
    const int tid = threadIdx.x;
    {
        float4* a4 = (float4*)acc;
        #pragma unroll
        for (int i = 0; i < (BKT_NODES * OUT_F / 4) / 256; ++i)
            a4[tid + i * 256] = make_float4(0.f, 0.f, 0.f, 0.f);
    }
    __syncthreads();

    const int start = bases[b * nSB];
    const int end = (b + 1 < NB) ? bases[(b + 1) * nSB] : nE;
    const int wv = tid >> 6;
    const int lane = tid & 63;
    const ushort* hu = (const ushort*)h;

    // 8-edge groups, wave-strided
    for (int e0 = start + wv * 8; e0 + 8 <= end; e0 += 32) {
        int2 pk[8];
        #pragma unroll
        for (int i = 0; i < 8; ++i) pk[i] = pack[e0 + i];  // wave-uniform
        ushort hv[8];
        #pragma unroll
        for (int i = 0; i < 8; ++i) {
            int s = pk[i].x & 0x1FFFF;
            hv[i] = hu[(size_t)s * OUT_F + lane];
        }
        #pragma unroll
        for (int i = 0; i < 8; ++i) {
            int dl = (pk[i].x >> 17) & (BKT_NODES - 1);
            float ww = __int_as_float(pk[i].y);
            atomicAdd(&acc[dl * OUT_F + lane], ww * bf2f((short)hv[i]));
        }
    }
    // remainder (< 8 edges), wave 0 only
    if (wv == 0) {
        int total = end - start;
        for (int e = start + (total & ~7); e < end; ++e) {
            int2 p = pack[e];
            int s = p.x & 0x1FFFF;
            int dl = (p.x >> 17) & (BKT_NODES - 1);
            float ww = __int_as_float(p.y);
            atomicAdd(&acc[dl * OUT_F + lane],
                      ww * bf2f((short)hu[(size_t)s * OUT_F + lane]));
        }
    }
    __syncthreads();

    const int node0 = b * BKT_NODES;
    const int ncnt = min(BKT_NODES, nRows - node0);
    float4* o4 = (float4*)(out + (size_t)node0 * OUT_F);
    const float4* a4 = (const float4*)acc;
    for (int i = tid; i < ncnt * (OUT_F / 4); i += 256) o4[i] = a4[i];
}

// ---------------- fallback (atomic) scatter ----------------
__global__ __launch_bounds__(256)
void scatter_kernel(const short* __restrict__ h, const int* __restrict__ src,
                    const int* __restrict__ dst, const float* __restrict__ w,
                    float* __restrict__ out, int nE) {
    int t = blockIdx.x * 256 + threadIdx.x;
    int c = t & 15;
    int stride = (gridDim.x * 256) >> 4;
    for (int e = t >> 4; e < nE; e += stride) {
        int s = src[e];
        int d = dst[e];
        float ww = w[e];
        float* op = out + (size_t)d * OUT_F + c * 4;
        const short* hp = h + (size_t)s * OUT_F + c * 4;
        unsafeAtomicAdd(op + 0, ww * bf2f(hp[0]));
        unsafeAtomicAdd(op + 1, ww * bf2f(hp[1]));
        unsafeAtomicAdd(op + 2, ww * bf2f(hp[2]));
        unsafeAtomicAdd(op + 3, ww * bf2f(hp[3]));
    }
}

static inline size_t align256(size_t x) { return (x + 255) & ~(size_t)255; }

extern "C" void kernel_launch(void* const* d_in, const int* in_sizes, int n_in,
                              void* d_out, int out_size, void* d_ws, size_t ws_size,
                              hipStream_t stream) {
    const float* x    = (const float*)d_in[0];
    const int*   esrc = (const int*)d_in[1];
    const int*   edst = (const int*)d_in[2];
    const float* ew   = (const float*)d_in[3];
    const float* W    = (const float*)d_in[4];
    const float* b    = (const float*)d_in[5];

    int nRows = in_sizes[0] / IN_F;   // 100000
    int nE    = in_sizes[1];          // 1600000

    int NB  = (nRows + BKT_NODES - 1) / BKT_NODES;   // 782
    int nSB = (nE + SORT_CHUNK - 1) / SORT_CHUNK;    // 98
    int nCnt = NB * nSB;                             // 76636
    int nPart = (nCnt + 1023) / 1024;                // 75

    // workspace layout
    char* p = (char*)d_ws;
    size_t hB    = align256((size_t)nRows * OUT_F * sizeof(short));
    size_t wtB   = align256((size_t)IN_F * OUT_F * sizeof(short));
    size_t cntB  = align256((size_t)nCnt * sizeof(int));
    size_t basB  = align256((size_t)nCnt * sizeof(int));
    size_t partB = align256((size_t)nPart * sizeof(int));
    size_t packB = align256((size_t)nE * sizeof(int2));
    size_t need  = hB + wtB + cntB + basB + partB + packB;

    short* h      = (short*)p;  p += hB;
    short* Wt     = (short*)p;  p += wtB;
    int*   counts = (int*)p;    p += cntB;
    int*   bases  = (int*)p;    p += basB;
    int*   part   = (int*)p;    p += partB;
    int2*  pack   = (int2*)p;

    float* out = (float*)d_out;

    prep_w_kernel<<<(IN_F * OUT_F + 255) / 256, 256, 0, stream>>>(W, Wt);
    int fcBlocks = (nRows + 127) / 128;
    fc_mfma_kernel<<<fcBlocks, 256, 0, stream>>>(x, Wt, b, h, nRows);

    bool ok = (ws_size >= need) && (NB <= MAX_NB) && (nPart <= 128) &&
              (nRows < (1 << 17));
    if (ok) {
        bhist_kernel<<<nSB, 256, 0, stream>>>(edst, counts, nE, NB, nSB);
        scan1_kernel<<<nPart, 256, 0, stream>>>(counts, bases, part, nCnt);
        scan2_kernel<<<1, 128, 0, stream>>>(part, nPart);
        scan3_kernel<<<512, 256, 0, stream>>>(bases, part, nCnt);
        bfill_kernel<<<nSB, 256, 0, stream>>>(esrc, edst, ew, bases, pack,
                                              nE, NB, nSB);
        bgather_kernel<<<NB, 256, 0, stream>>>(h, bases, pack, out,
                                               nRows, nE, NB, nSB);
    } else {
        hipMemsetAsync(out, 0, (size_t)out_size * sizeof(float), stream);
        scatter_kernel<<<4096, 256, 0, stream>>>(h, esrc, edst, ew, out, nE);
    }
}

// Round 6
// 351.573 us; speedup vs baseline: 2.7161x; 2.7161x over previous
//
#include <hip/hip_runtime.h>

#define IN_F 256
#define OUT_F 64
#define SORT_CHUNK 16384
#define BKT_SHIFT 7
#define BKT_NODES 128
#define MAX_NB 1024

typedef __attribute__((ext_vector_type(8))) short short8;
typedef __attribute__((ext_vector_type(4))) float f32x4;

static __device__ __forceinline__ short f2bf(float f) {
    union { float f; unsigned u; } v; v.f = f;
    unsigned r = v.u + 0x7FFFu + ((v.u >> 16) & 1u);  // RNE
    return (short)(r >> 16);
}
static __device__ __forceinline__ float bf2f(short s) {
    return __int_as_float(((unsigned)(unsigned short)s) << 16);
}

// ---------------- prep: Wt[n][k] = bf16(W[k][n]) ----------------
__global__ __launch_bounds__(256)
void prep_w_kernel(const float* __restrict__ W, short* __restrict__ Wt) {
    int i = blockIdx.x * 256 + threadIdx.x;
    if (i < IN_F * OUT_F) {
        int k = i / OUT_F, n = i % OUT_F;
        Wt[n * IN_F + k] = f2bf(W[i]);
    }
}

// ---------------- fc: h(bf16) = x @ W + b via MFMA ----------------
__global__ __launch_bounds__(256, 4)
void fc_mfma_kernel(const float* __restrict__ x, const short* __restrict__ Wt,
                    const float* __restrict__ b, short* __restrict__ h, int nRows) {
    __shared__ short Wl[OUT_F * IN_F];  // 32 KB, swizzled
    {
        const uint4* src = (const uint4*)Wt;  // 2048 16B slots
        #pragma unroll
        for (int it = 0; it < 8; ++it) {
            int g = it * 256 + threadIdx.x;
            int n = g >> 5, s = g & 31;
            *(uint4*)((char*)Wl + n * 512 + (s ^ (n & 7)) * 16) = src[g];
        }
    }
    __syncthreads();

    const int wv = threadIdx.x >> 6;
    const int l  = threadIdx.x & 63;
    const int lr = l & 15;
    const int kg = l >> 4;

    const int rowbase = (blockIdx.x * 4 + wv) * 32;
    if (rowbase >= nRows) return;

    const int ar0 = min(rowbase + lr,      nRows - 1);
    const int ar1 = min(rowbase + 16 + lr, nRows - 1);
    const float* xp0 = x + (size_t)ar0 * IN_F + kg * 8;
    const float* xp1 = x + (size_t)ar1 * IN_F + kg * 8;

    f32x4 acc[2][4];
    #pragma unroll
    for (int m = 0; m < 2; ++m)
        #pragma unroll
        for (int n = 0; n < 4; ++n) acc[m][n] = (f32x4)0.f;

    #pragma unroll
    for (int kt = 0; kt < 8; ++kt) {
        const int K0 = kt * 32;
        float4 a0lo = *(const float4*)(xp0 + K0);
        float4 a0hi = *(const float4*)(xp0 + K0 + 4);
        float4 a1lo = *(const float4*)(xp1 + K0);
        float4 a1hi = *(const float4*)(xp1 + K0 + 4);

        short8 a0, a1;
        a0[0] = f2bf(a0lo.x); a0[1] = f2bf(a0lo.y);
        a0[2] = f2bf(a0lo.z); a0[3] = f2bf(a0lo.w);
        a0[4] = f2bf(a0hi.x); a0[5] = f2bf(a0hi.y);
        a0[6] = f2bf(a0hi.z); a0[7] = f2bf(a0hi.w);
        a1[0] = f2bf(a1lo.x); a1[1] = f2bf(a1lo.y);
        a1[2] = f2bf(a1lo.z); a1[3] = f2bf(a1lo.w);
        a1[4] = f2bf(a1hi.x); a1[5] = f2bf(a1hi.y);
        a1[6] = f2bf(a1hi.z); a1[7] = f2bf(a1hi.w);

        short8 bf[4];
        #pragma unroll
        for (int nt = 0; nt < 4; ++nt) {
            const int col = nt * 16 + lr;
            const int slot = (kt * 4 + kg) ^ (col & 7);
            bf[nt] = *(const short8*)((const char*)Wl + col * 512 + slot * 16);
        }
        #pragma unroll
        for (int nt = 0; nt < 4; ++nt) {
            acc[0][nt] = __builtin_amdgcn_mfma_f32_16x16x32_bf16(a0, bf[nt], acc[0][nt], 0, 0, 0);
            acc[1][nt] = __builtin_amdgcn_mfma_f32_16x16x32_bf16(a1, bf[nt], acc[1][nt], 0, 0, 0);
        }
    }

    #pragma unroll
    for (int m = 0; m < 2; ++m) {
        #pragma unroll
        for (int nt = 0; nt < 4; ++nt) {
            const int col = nt * 16 + lr;
            const float bias = b[col];
            #pragma unroll
            for (int j = 0; j < 4; ++j) {
                const int r = rowbase + m * 16 + kg * 4 + j;
                if (r < nRows)
                    h[(size_t)r * OUT_F + col] = f2bf(acc[m][nt][j] + bias);
            }
        }
    }
}

// ---------------- bucket counting sort (level 1) ----------------
__global__ __launch_bounds__(256)
void bhist_kernel(const int* __restrict__ dst, int* __restrict__ counts,
                  int nE, int NB, int nSB) {
    __shared__ int lh[MAX_NB];
    for (int b = threadIdx.x; b < NB; b += 256) lh[b] = 0;
    __syncthreads();
    int base = blockIdx.x * SORT_CHUNK;
    int lim = min(nE, base + SORT_CHUNK);
    for (int e = base + threadIdx.x; e < lim; e += 256)
        atomicAdd(&lh[dst[e] >> BKT_SHIFT], 1);
    __syncthreads();
    for (int b = threadIdx.x; b < NB; b += 256)
        counts[b * nSB + blockIdx.x] = lh[b];
}

__global__ __launch_bounds__(256)
void scan1_kernel(const int* __restrict__ cnt, int* __restrict__ off,
                  int* __restrict__ part, int n) {
    __shared__ int sh[256];
    int base = blockIdx.x * 1024;
    int t = threadIdx.x;
    int v[4]; int s = 0;
    #pragma unroll
    for (int i = 0; i < 4; ++i) {
        int idx = base + t * 4 + i;
        v[i] = (idx < n) ? cnt[idx] : 0;
        s += v[i];
    }
    sh[t] = s;
    __syncthreads();
    for (int d = 1; d < 256; d <<= 1) {
        int val = (t >= d) ? sh[t - d] : 0;
        __syncthreads();
        sh[t] += val;
        __syncthreads();
    }
    if (t == 255) part[blockIdx.x] = sh[255];
    int run = (t == 0) ? 0 : sh[t - 1];
    #pragma unroll
    for (int i = 0; i < 4; ++i) {
        int idx = base + t * 4 + i;
        if (idx < n) off[idx] = run;
        run += v[i];
    }
}

__global__ __launch_bounds__(128)
void scan2_kernel(int* __restrict__ part, int nPart) {
    __shared__ int sh[128];
    int t = threadIdx.x;
    sh[t] = (t < nPart) ? part[t] : 0;
    __syncthreads();
    for (int d = 1; d < 128; d <<= 1) {
        int val = (t >= d) ? sh[t - d] : 0;
        __syncthreads();
        sh[t] += val;
        __syncthreads();
    }
    if (t < nPart) part[t] = (t == 0) ? 0 : sh[t - 1];
}

__global__ __launch_bounds__(256)
void scan3_kernel(int* __restrict__ off, const int* __restrict__ part, int n) {
    for (int i = blockIdx.x * blockDim.x + threadIdx.x; i < n;
         i += gridDim.x * blockDim.x)
        off[i] += part[i >> 10];
}

// pack = (src | dstlow<<17, w), bucket-ordered
__global__ __launch_bounds__(256)
void bfill_kernel(const int* __restrict__ src, const int* __restrict__ dst,
                  const float* __restrict__ w, const int* __restrict__ bases,
                  int2* __restrict__ pack, int nE, int NB, int nSB) {
    __shared__ int cur[MAX_NB];
    for (int b = threadIdx.x; b < NB; b += 256)
        cur[b] = bases[b * nSB + blockIdx.x];
    __syncthreads();
    int base = blockIdx.x * SORT_CHUNK;
    int lim = min(nE, base + SORT_CHUNK);
    for (int e = base + threadIdx.x; e < lim; e += 256) {
        int d = dst[e];
        int p = atomicAdd(&cur[d >> BKT_SHIFT], 1);
        pack[p] = make_int2(src[e] | ((d & (BKT_NODES - 1)) << 17),
                            __float_as_int(w[e]));
    }
}

// ---------------- nsort (level 2): node-sort within bucket ----------------
// One block per bucket. LDS 128-counter histogram -> scan -> per-node CSR
// offsets (off[]) -> re-scatter segment into node-sorted pack2 (writes land
// within the segment's ~16KB window -> L2-merged).
__global__ __launch_bounds__(256)
void nsort_kernel(const int2* __restrict__ pack, const int* __restrict__ bases,
                  int2* __restrict__ pack2, int* __restrict__ off,
                  int nRows, int nE, int NB, int nSB) {
    __shared__ int cnt[BKT_NODES];
    __shared__ int scn[BKT_NODES];
    const int b = blockIdx.x;
    const int tid = threadIdx.x;
    const int segStart = bases[b * nSB];
    const int segEnd = (b + 1 < NB) ? bases[(b + 1) * nSB] : nE;

    if (tid < BKT_NODES) cnt[tid] = 0;
    __syncthreads();
    for (int e = segStart + tid; e < segEnd; e += 256)
        atomicAdd(&cnt[(pack[e].x >> 17) & (BKT_NODES - 1)], 1);
    __syncthreads();

    // inclusive scan of cnt into scn (Hillis-Steele, 128 entries)
    if (tid < BKT_NODES) scn[tid] = cnt[tid];
    __syncthreads();
    for (int d = 1; d < BKT_NODES; d <<= 1) {
        int t = 0;
        if (tid < BKT_NODES && tid >= d) t = scn[tid - d];
        __syncthreads();
        if (tid < BKT_NODES) scn[tid] += t;
        __syncthreads();
    }

    const int node0 = b * BKT_NODES;
    const int ncnt = min(BKT_NODES, nRows - node0);
    if (tid < ncnt)
        off[node0 + tid] = segStart + scn[tid] - cnt[tid];  // exclusive
    if (tid == 0 && node0 + ncnt == nRows)
        off[nRows] = segEnd;
    __syncthreads();

    // cursors (reuse cnt)
    if (tid < BKT_NODES) cnt[tid] = segStart + scn[tid] - cnt[tid];
    __syncthreads();
    for (int e = segStart + tid; e < segEnd; e += 256) {
        int2 p = pack[e];
        int dl = (p.x >> 17) & (BKT_NODES - 1);
        int q = atomicAdd(&cnt[dl], 1);
        pack2[q] = make_int2(p.x & 0x1FFFF, p.y);
    }
}

// ---------------- ngather: one wave per node ----------------
__global__ __launch_bounds__(256)
void ngather_kernel(const short* __restrict__ h, const int* __restrict__ off,
                    const int2* __restrict__ pack2, float* __restrict__ out,
                    int nNodes) {
    int wid = (blockIdx.x * 256 + threadIdx.x) >> 6;
    int lane = threadIdx.x & 63;
    if (wid >= nNodes) return;
    int e = off[wid], end = off[wid + 1];
    const ushort* hu = (const ushort*)h;
    float acc = 0.f;
    for (; e + 8 <= end; e += 8) {
        int2 pk[8];
        #pragma unroll
        for (int i = 0; i < 8; ++i) pk[i] = pack2[e + i];  // wave-uniform, 64B
        float hv[8];
        #pragma unroll
        for (int i = 0; i < 8; ++i)
            hv[i] = bf2f((short)hu[(size_t)pk[i].x * OUT_F + lane]);
        #pragma unroll
        for (int i = 0; i < 8; ++i)
            acc = fmaf(__int_as_float(pk[i].y), hv[i], acc);
    }
    for (; e + 4 <= end; e += 4) {
        int2 pk[4];
        #pragma unroll
        for (int i = 0; i < 4; ++i) pk[i] = pack2[e + i];
        #pragma unroll
        for (int i = 0; i < 4; ++i)
            acc = fmaf(__int_as_float(pk[i].y),
                       bf2f((short)hu[(size_t)pk[i].x * OUT_F + lane]), acc);
    }
    for (; e < end; ++e) {
        int2 p = pack2[e];
        acc = fmaf(__int_as_float(p.y),
                   bf2f((short)hu[(size_t)p.x * OUT_F + lane]), acc);
    }
    out[(size_t)wid * OUT_F + lane] = acc;
}

// ---------------- fallback (atomic) scatter ----------------
__global__ __launch_bounds__(256)
void scatter_kernel(const short* __restrict__ h, const int* __restrict__ src,
                    const int* __restrict__ dst, const float* __restrict__ w,
                    float* __restrict__ out, int nE) {
    int t = blockIdx.x * 256 + threadIdx.x;
    int c = t & 15;
    int stride = (gridDim.x * 256) >> 4;
    for (int e = t >> 4; e < nE; e += stride) {
        int s = src[e];
        int d = dst[e];
        float ww = w[e];
        float* op = out + (size_t)d * OUT_F + c * 4;
        const short* hp = h + (size_t)s * OUT_F + c * 4;
        unsafeAtomicAdd(op + 0, ww * bf2f(hp[0]));
        unsafeAtomicAdd(op + 1, ww * bf2f(hp[1]));
        unsafeAtomicAdd(op + 2, ww * bf2f(hp[2]));
        unsafeAtomicAdd(op + 3, ww * bf2f(hp[3]));
    }
}

static inline size_t align256(size_t x) { return (x + 255) & ~(size_t)255; }

extern "C" void kernel_launch(void* const* d_in, const int* in_sizes, int n_in,
                              void* d_out, int out_size, void* d_ws, size_t ws_size,
                              hipStream_t stream) {
    const float* x    = (const float*)d_in[0];
    const int*   esrc = (const int*)d_in[1];
    const int*   edst = (const int*)d_in[2];
    const float* ew   = (const float*)d_in[3];
    const float* W    = (const float*)d_in[4];
    const float* b    = (const float*)d_in[5];

    int nRows = in_sizes[0] / IN_F;   // 100000
    int nE    = in_sizes[1];          // 1600000

    int NB  = (nRows + BKT_NODES - 1) / BKT_NODES;   // 782
    int nSB = (nE + SORT_CHUNK - 1) / SORT_CHUNK;    // 98
    int nCnt = NB * nSB;                             // 76636
    int nPart = (nCnt + 1023) / 1024;                // 75

    // workspace layout
    char* p = (char*)d_ws;
    size_t hB    = align256((size_t)nRows * OUT_F * sizeof(short));
    size_t wtB   = align256((size_t)IN_F * OUT_F * sizeof(short));
    size_t cntB  = align256((size_t)nCnt * sizeof(int));
    size_t basB  = align256((size_t)nCnt * sizeof(int));
    size_t partB = align256((size_t)nPart * sizeof(int));
    size_t packB = align256((size_t)nE * sizeof(int2));
    size_t offB  = align256((size_t)(nRows + 1) * sizeof(int));
    size_t need  = hB + wtB + cntB + basB + partB + 2 * packB + offB;

    short* h      = (short*)p;  p += hB;
    short* Wt     = (short*)p;  p += wtB;
    int*   counts = (int*)p;    p += cntB;
    int*   bases  = (int*)p;    p += basB;
    int*   part   = (int*)p;    p += partB;
    int2*  pack   = (int2*)p;   p += packB;
    int2*  pack2  = (int2*)p;   p += packB;
    int*   off    = (int*)p;

    float* out = (float*)d_out;

    prep_w_kernel<<<(IN_F * OUT_F + 255) / 256, 256, 0, stream>>>(W, Wt);
    int fcBlocks = (nRows + 127) / 128;
    fc_mfma_kernel<<<fcBlocks, 256, 0, stream>>>(x, Wt, b, h, nRows);

    bool ok = (ws_size >= need) && (NB <= MAX_NB) && (nPart <= 128) &&
              (nRows < (1 << 17));
    if (ok) {
        bhist_kernel<<<nSB, 256, 0, stream>>>(edst, counts, nE, NB, nSB);
        scan1_kernel<<<nPart, 256, 0, stream>>>(counts, bases, part, nCnt);
        scan2_kernel<<<1, 128, 0, stream>>>(part, nPart);
        scan3_kernel<<<512, 256, 0, stream>>>(bases, part, nCnt);
        bfill_kernel<<<nSB, 256, 0, stream>>>(esrc, edst, ew, bases, pack,
                                              nE, NB, nSB);
        nsort_kernel<<<NB, 256, 0, stream>>>(pack, bases, pack2, off,
                                             nRows, nE, NB, nSB);
        int gBlocks = (nRows * 64 + 255) / 256;
        ngather_kernel<<<gBlocks, 256, 0, stream>>>(h, off, pack2, out, nRows);
    } else {
        hipMemsetAsync(out, 0, (size_t)out_size * sizeof(float), stream);
        scatter_kernel<<<4096, 256, 0, stream>>>(h, esrc, edst, ew, out, nE);
    }
}

// Round 7
// 307.174 us; speedup vs baseline: 3.1086x; 1.1445x over previous
//
#include <hip/hip_runtime.h>

#define IN_F 256
#define OUT_F 64
#define SORT_CHUNK 4096
#define BKT_SHIFT 7
#define BKT_NODES 128
#define MAX_NB 1024

typedef __attribute__((ext_vector_type(8))) short short8;
typedef __attribute__((ext_vector_type(4))) float f32x4;

static __device__ __forceinline__ short f2bf(float f) {
    union { float f; unsigned u; } v; v.f = f;
    unsigned r = v.u + 0x7FFFu + ((v.u >> 16) & 1u);  // RNE
    return (short)(r >> 16);
}
static __device__ __forceinline__ float bf2f(short s) {
    return __int_as_float(((unsigned)(unsigned short)s) << 16);
}

// ---------------- prep: Wt[n][k] = bf16(W[k][n]) ----------------
__global__ __launch_bounds__(256)
void prep_w_kernel(const float* __restrict__ W, short* __restrict__ Wt) {
    int i = blockIdx.x * 256 + threadIdx.x;
    if (i < IN_F * OUT_F) {
        int k = i / OUT_F, n = i % OUT_F;
        Wt[n * IN_F + k] = f2bf(W[i]);
    }
}

// ---------------- fc: h(bf16) = x @ W + b via MFMA ----------------
__global__ __launch_bounds__(256, 4)
void fc_mfma_kernel(const float* __restrict__ x, const short* __restrict__ Wt,
                    const float* __restrict__ b, short* __restrict__ h, int nRows) {
    __shared__ short Wl[OUT_F * IN_F];  // 32 KB, swizzled
    {
        const uint4* src = (const uint4*)Wt;  // 2048 16B slots
        #pragma unroll
        for (int it = 0; it < 8; ++it) {
            int g = it * 256 + threadIdx.x;
            int n = g >> 5, s = g & 31;
            *(uint4*)((char*)Wl + n * 512 + (s ^ (n & 7)) * 16) = src[g];
        }
    }
    __syncthreads();

    const int wv = threadIdx.x >> 6;
    const int l  = threadIdx.x & 63;
    const int lr = l & 15;
    const int kg = l >> 4;

    const int rowbase = (blockIdx.x * 4 + wv) * 32;
    if (rowbase >= nRows) return;

    const int ar0 = min(rowbase + lr,      nRows - 1);
    const int ar1 = min(rowbase + 16 + lr, nRows - 1);
    const float* xp0 = x + (size_t)ar0 * IN_F + kg * 8;
    const float* xp1 = x + (size_t)ar1 * IN_F + kg * 8;

    f32x4 acc[2][4];
    #pragma unroll
    for (int m = 0; m < 2; ++m)
        #pragma unroll
        for (int n = 0; n < 4; ++n) acc[m][n] = (f32x4)0.f;

    #pragma unroll
    for (int kt = 0; kt < 8; ++kt) {
        const int K0 = kt * 32;
        float4 a0lo = *(const float4*)(xp0 + K0);
        float4 a0hi = *(const float4*)(xp0 + K0 + 4);
        float4 a1lo = *(const float4*)(xp1 + K0);
        float4 a1hi = *(const float4*)(xp1 + K0 + 4);

        short8 a0, a1;
        a0[0] = f2bf(a0lo.x); a0[1] = f2bf(a0lo.y);
        a0[2] = f2bf(a0lo.z); a0[3] = f2bf(a0lo.w);
        a0[4] = f2bf(a0hi.x); a0[5] = f2bf(a0hi.y);
        a0[6] = f2bf(a0hi.z); a0[7] = f2bf(a0hi.w);
        a1[0] = f2bf(a1lo.x); a1[1] = f2bf(a1lo.y);
        a1[2] = f2bf(a1lo.z); a1[3] = f2bf(a1lo.w);
        a1[4] = f2bf(a1hi.x); a1[5] = f2bf(a1hi.y);
        a1[6] = f2bf(a1hi.z); a1[7] = f2bf(a1hi.w);

        short8 bf[4];
        #pragma unroll
        for (int nt = 0; nt < 4; ++nt) {
            const int col = nt * 16 + lr;
            const int slot = (kt * 4 + kg) ^ (col & 7);
            bf[nt] = *(const short8*)((const char*)Wl + col * 512 + slot * 16);
        }
        #pragma unroll
        for (int nt = 0; nt < 4; ++nt) {
            acc[0][nt] = __builtin_amdgcn_mfma_f32_16x16x32_bf16(a0, bf[nt], acc[0][nt], 0, 0, 0);
            acc[1][nt] = __builtin_amdgcn_mfma_f32_16x16x32_bf16(a1, bf[nt], acc[1][nt], 0, 0, 0);
        }
    }

    #pragma unroll
    for (int m = 0; m < 2; ++m) {
        #pragma unroll
        for (int nt = 0; nt < 4; ++nt) {
            const int col = nt * 16 + lr;
            const float bias = b[col];
            #pragma unroll
            for (int j = 0; j < 4; ++j) {
                const int r = rowbase + m * 16 + kg * 4 + j;
                if (r < nRows)
                    h[(size_t)r * OUT_F + col] = f2bf(acc[m][nt][j] + bias);
            }
        }
    }
}

// ---------------- bucket counting sort (level 1) ----------------
__global__ __launch_bounds__(256)
void bhist_kernel(const int* __restrict__ dst, int* __restrict__ counts,
                  int nE, int NB, int nSB) {
    __shared__ int lh[MAX_NB];
    for (int b = threadIdx.x; b < NB; b += 256) lh[b] = 0;
    __syncthreads();
    int base = blockIdx.x * SORT_CHUNK;
    int lim = min(nE, base + SORT_CHUNK);
    for (int e = base + threadIdx.x; e < lim; e += 256)
        atomicAdd(&lh[dst[e] >> BKT_SHIFT], 1);
    __syncthreads();
    for (int b = threadIdx.x; b < NB; b += 256)
        counts[b * nSB + blockIdx.x] = lh[b];
}

__global__ __launch_bounds__(256)
void scan1_kernel(const int* __restrict__ cnt, int* __restrict__ off,
                  int* __restrict__ part, int n) {
    __shared__ int sh[256];
    int base = blockIdx.x * 1024;
    int t = threadIdx.x;
    int v[4]; int s = 0;
    #pragma unroll
    for (int i = 0; i < 4; ++i) {
        int idx = base + t * 4 + i;
        v[i] = (idx < n) ? cnt[idx] : 0;
        s += v[i];
    }
    sh[t] = s;
    __syncthreads();
    for (int d = 1; d < 256; d <<= 1) {
        int val = (t >= d) ? sh[t - d] : 0;
        __syncthreads();
        sh[t] += val;
        __syncthreads();
    }
    if (t == 255) part[blockIdx.x] = sh[255];
    int run = (t == 0) ? 0 : sh[t - 1];
    #pragma unroll
    for (int i = 0; i < 4; ++i) {
        int idx = base + t * 4 + i;
        if (idx < n) off[idx] = run;
        run += v[i];
    }
}

// exclusive scan of up to 1024 partials, in place (256 thr x 4 elems)
__global__ __launch_bounds__(256)
void scan2_kernel(int* __restrict__ part, int nPart) {
    __shared__ int sh[256];
    int t = threadIdx.x;
    int v[4]; int s = 0;
    #pragma unroll
    for (int i = 0; i < 4; ++i) {
        int idx = t * 4 + i;
        v[i] = (idx < nPart) ? part[idx] : 0;
        s += v[i];
    }
    sh[t] = s;
    __syncthreads();
    for (int d = 1; d < 256; d <<= 1) {
        int val = (t >= d) ? sh[t - d] : 0;
        __syncthreads();
        sh[t] += val;
        __syncthreads();
    }
    int run = (t == 0) ? 0 : sh[t - 1];
    #pragma unroll
    for (int i = 0; i < 4; ++i) {
        int idx = t * 4 + i;
        if (idx < nPart) part[idx] = run;
        run += v[i];
    }
}

__global__ __launch_bounds__(256)
void scan3_kernel(int* __restrict__ off, const int* __restrict__ part, int n) {
    for (int i = blockIdx.x * blockDim.x + threadIdx.x; i < n;
         i += gridDim.x * blockDim.x)
        off[i] += part[i >> 10];
}

// pack = (src | dstlow<<17, w), bucket-ordered
__global__ __launch_bounds__(256)
void bfill_kernel(const int* __restrict__ src, const int* __restrict__ dst,
                  const float* __restrict__ w, const int* __restrict__ bases,
                  int2* __restrict__ pack, int nE, int NB, int nSB) {
    __shared__ int cur[MAX_NB];
    for (int b = threadIdx.x; b < NB; b += 256)
        cur[b] = bases[b * nSB + blockIdx.x];
    __syncthreads();
    int base = blockIdx.x * SORT_CHUNK;
    int lim = min(nE, base + SORT_CHUNK);
    for (int e = base + threadIdx.x; e < lim; e += 256) {
        int d = dst[e];
        int p = atomicAdd(&cur[d >> BKT_SHIFT], 1);
        pack[p] = make_int2(src[e] | ((d & (BKT_NODES - 1)) << 17),
                            __float_as_int(w[e]));
    }
}

// ---------------- nsort (level 2): node-sort within bucket ----------------
__global__ __launch_bounds__(256)
void nsort_kernel(const int2* __restrict__ pack, const int* __restrict__ bases,
                  int2* __restrict__ pack2, int* __restrict__ off,
                  int nRows, int nE, int NB, int nSB) {
    __shared__ int cnt[BKT_NODES];
    __shared__ int scn[BKT_NODES];
    const int b = blockIdx.x;
    const int tid = threadIdx.x;
    const int segStart = bases[b * nSB];
    const int segEnd = (b + 1 < NB) ? bases[(b + 1) * nSB] : nE;

    if (tid < BKT_NODES) cnt[tid] = 0;
    __syncthreads();
    for (int e = segStart + tid; e < segEnd; e += 256)
        atomicAdd(&cnt[(pack[e].x >> 17) & (BKT_NODES - 1)], 1);
    __syncthreads();

    if (tid < BKT_NODES) scn[tid] = cnt[tid];
    __syncthreads();
    for (int d = 1; d < BKT_NODES; d <<= 1) {
        int t = 0;
        if (tid < BKT_NODES && tid >= d) t = scn[tid - d];
        __syncthreads();
        if (tid < BKT_NODES) scn[tid] += t;
        __syncthreads();
    }

    const int node0 = b * BKT_NODES;
    const int ncnt = min(BKT_NODES, nRows - node0);
    if (tid < ncnt)
        off[node0 + tid] = segStart + scn[tid] - cnt[tid];  // exclusive
    if (tid == 0 && node0 + ncnt == nRows)
        off[nRows] = segEnd;
    __syncthreads();

    if (tid < BKT_NODES) cnt[tid] = segStart + scn[tid] - cnt[tid];
    __syncthreads();
    for (int e = segStart + tid; e < segEnd; e += 256) {
        int2 p = pack[e];
        int dl = (p.x >> 17) & (BKT_NODES - 1);
        int q = atomicAdd(&cnt[dl], 1);
        pack2[q] = make_int2(p.x & 0x1FFFF, p.y);
    }
}

// ---------------- ngather: one wave per node ----------------
__global__ __launch_bounds__(256)
void ngather_kernel(const short* __restrict__ h, const int* __restrict__ off,
                    const int2* __restrict__ pack2, float* __restrict__ out,
                    int nNodes) {
    int wid = (blockIdx.x * 256 + threadIdx.x) >> 6;
    int lane = threadIdx.x & 63;
    if (wid >= nNodes) return;
    int e = off[wid], end = off[wid + 1];
    const ushort* hu = (const ushort*)h;
    float acc = 0.f;
    for (; e + 8 <= end; e += 8) {
        int2 pk[8];
        #pragma unroll
        for (int i = 0; i < 8; ++i) pk[i] = pack2[e + i];  // wave-uniform, 64B
        float hv[8];
        #pragma unroll
        for (int i = 0; i < 8; ++i)
            hv[i] = bf2f((short)hu[(size_t)pk[i].x * OUT_F + lane]);
        #pragma unroll
        for (int i = 0; i < 8; ++i)
            acc = fmaf(__int_as_float(pk[i].y), hv[i], acc);
    }
    for (; e + 4 <= end; e += 4) {
        int2 pk[4];
        #pragma unroll
        for (int i = 0; i < 4; ++i) pk[i] = pack2[e + i];
        #pragma unroll
        for (int i = 0; i < 4; ++i)
            acc = fmaf(__int_as_float(pk[i].y),
                       bf2f((short)hu[(size_t)pk[i].x * OUT_F + lane]), acc);
    }
    for (; e < end; ++e) {
        int2 p = pack2[e];
        acc = fmaf(__int_as_float(p.y),
                   bf2f((short)hu[(size_t)p.x * OUT_F + lane]), acc);
    }
    out[(size_t)wid * OUT_F + lane] = acc;
}

// ---------------- fallback (atomic) scatter ----------------
__global__ __launch_bounds__(256)
void scatter_kernel(const short* __restrict__ h, const int* __restrict__ src,
                    const int* __restrict__ dst, const float* __restrict__ w,
                    float* __restrict__ out, int nE) {
    int t = blockIdx.x * 256 + threadIdx.x;
    int c = t & 15;
    int stride = (gridDim.x * 256) >> 4;
    for (int e = t >> 4; e < nE; e += stride) {
        int s = src[e];
        int d = dst[e];
        float ww = w[e];
        float* op = out + (size_t)d * OUT_F + c * 4;
        const short* hp = h + (size_t)s * OUT_F + c * 4;
        unsafeAtomicAdd(op + 0, ww * bf2f(hp[0]));
        unsafeAtomicAdd(op + 1, ww * bf2f(hp[1]));
        unsafeAtomicAdd(op + 2, ww * bf2f(hp[2]));
        unsafeAtomicAdd(op + 3, ww * bf2f(hp[3]));
    }
}

static inline size_t align256(size_t x) { return (x + 255) & ~(size_t)255; }

extern "C" void kernel_launch(void* const* d_in, const int* in_sizes, int n_in,
                              void* d_out, int out_size, void* d_ws, size_t ws_size,
                              hipStream_t stream) {
    const float* x    = (const float*)d_in[0];
    const int*   esrc = (const int*)d_in[1];
    const int*   edst = (const int*)d_in[2];
    const float* ew   = (const float*)d_in[3];
    const float* W    = (const float*)d_in[4];
    const float* b    = (const float*)d_in[5];

    int nRows = in_sizes[0] / IN_F;   // 100000
    int nE    = in_sizes[1];          // 1600000

    int NB  = (nRows + BKT_NODES - 1) / BKT_NODES;   // 782
    int nSB = (nE + SORT_CHUNK - 1) / SORT_CHUNK;    // 391
    int nCnt = NB * nSB;                             // 305762
    int nPart = (nCnt + 1023) / 1024;                // 299

    // workspace layout
    char* p = (char*)d_ws;
    size_t hB    = align256((size_t)nRows * OUT_F * sizeof(short));
    size_t wtB   = align256((size_t)IN_F * OUT_F * sizeof(short));
    size_t cntB  = align256((size_t)nCnt * sizeof(int));
    size_t basB  = align256((size_t)nCnt * sizeof(int));
    size_t partB = align256((size_t)nPart * sizeof(int));
    size_t packB = align256((size_t)nE * sizeof(int2));
    size_t offB  = align256((size_t)(nRows + 1) * sizeof(int));
    size_t need  = hB + wtB + cntB + basB + partB + 2 * packB + offB;

    short* h      = (short*)p;  p += hB;
    short* Wt     = (short*)p;  p += wtB;
    int*   counts = (int*)p;    p += cntB;
    int*   bases  = (int*)p;    p += basB;
    int*   part   = (int*)p;    p += partB;
    int2*  pack   = (int2*)p;   p += packB;
    int2*  pack2  = (int2*)p;   p += packB;
    int*   off    = (int*)p;

    float* out = (float*)d_out;

    prep_w_kernel<<<(IN_F * OUT_F + 255) / 256, 256, 0, stream>>>(W, Wt);
    int fcBlocks = (nRows + 127) / 128;
    fc_mfma_kernel<<<fcBlocks, 256, 0, stream>>>(x, Wt, b, h, nRows);

    bool ok = (ws_size >= need) && (NB <= MAX_NB) && (nPart <= 1024) &&
              (nRows < (1 << 17));
    if (ok) {
        bhist_kernel<<<nSB, 256, 0, stream>>>(edst, counts, nE, NB, nSB);
        scan1_kernel<<<nPart, 256, 0, stream>>>(counts, bases, part, nCnt);
        scan2_kernel<<<1, 256, 0, stream>>>(part, nPart);
        scan3_kernel<<<512, 256, 0, stream>>>(bases, part, nCnt);
        bfill_kernel<<<nSB, 256, 0, stream>>>(esrc, edst, ew, bases, pack,
                                              nE, NB, nSB);
        nsort_kernel<<<NB, 256, 0, stream>>>(pack, bases, pack2, off,
                                             nRows, nE, NB, nSB);
        int gBlocks = (nRows * 64 + 255) / 256;
        ngather_kernel<<<gBlocks, 256, 0, stream>>>(h, off, pack2, out, nRows);
    } else {
        hipMemsetAsync(out, 0, (size_t)out_size * sizeof(float), stream);
        scatter_kernel<<<4096, 256, 0, stream>>>(h, esrc, edst, ew, out, nE);
    }
}

// Round 8
// 286.449 us; speedup vs baseline: 3.3335x; 1.0724x over previous
//
#include <hip/hip_runtime.h>

#define IN_F 256
#define OUT_F 64
#define SORT_CHUNK 4096
#define BKT_SHIFT 7
#define BKT_NODES 128
#define MAX_NB 1024

typedef __attribute__((ext_vector_type(8))) short short8;
typedef __attribute__((ext_vector_type(4))) float f32x4;

static __device__ __forceinline__ short f2bf(float f) {
    union { float f; unsigned u; } v; v.f = f;
    unsigned r = v.u + 0x7FFFu + ((v.u >> 16) & 1u);  // RNE
    return (short)(r >> 16);
}
static __device__ __forceinline__ float bf2f(short s) {
    return __int_as_float(((unsigned)(unsigned short)s) << 16);
}

// ---------------- prep: Wt[n][k] = bf16(W[k][n]) ----------------
__global__ __launch_bounds__(256)
void prep_w_kernel(const float* __restrict__ W, short* __restrict__ Wt) {
    int i = blockIdx.x * 256 + threadIdx.x;
    if (i < IN_F * OUT_F) {
        int k = i / OUT_F, n = i % OUT_F;
        Wt[n * IN_F + k] = f2bf(W[i]);
    }
}

// ---------------- fused: fc (MFMA GEMM) || bhist (bucket histogram) -------
// blockIdx < nHist  -> histogram role over one 4096-edge chunk (int4 ILP)
// blockIdx >= nHist -> GEMM role (as round-4 fc_mfma)
// The sort pipeline is independent of h, so its first pass overlaps the
// BW-bound GEMM instead of serializing after it.
__global__ __launch_bounds__(256, 4)
void fc_bhist_kernel(const float* __restrict__ x, const short* __restrict__ Wt,
                     const float* __restrict__ bias, short* __restrict__ h,
                     const int* __restrict__ dst, int* __restrict__ counts,
                     int nRows, int nE, int NB, int nSB, int nHist) {
    __shared__ __align__(16) char smem[OUT_F * IN_F * sizeof(short)];  // 32 KB
    if ((int)blockIdx.x < nHist) {
        // ---- histogram role ----
        int* lh = (int*)smem;
        const int cb = blockIdx.x;
        for (int b0 = threadIdx.x; b0 < NB; b0 += 256) lh[b0] = 0;
        __syncthreads();
        const int base = cb * SORT_CHUNK;
        const int lim = min(nE, base + SORT_CHUNK);
        const int4* d4 = (const int4*)(dst + base);
        const int n4 = (lim - base) >> 2;
        for (int i = threadIdx.x; i < n4; i += 256) {
            int4 v = d4[i];
            atomicAdd(&lh[v.x >> BKT_SHIFT], 1);
            atomicAdd(&lh[v.y >> BKT_SHIFT], 1);
            atomicAdd(&lh[v.z >> BKT_SHIFT], 1);
            atomicAdd(&lh[v.w >> BKT_SHIFT], 1);
        }
        for (int e = base + (n4 << 2) + threadIdx.x; e < lim; e += 256)
            atomicAdd(&lh[dst[e] >> BKT_SHIFT], 1);
        __syncthreads();
        for (int b0 = threadIdx.x; b0 < NB; b0 += 256)
            counts[b0 * nSB + cb] = lh[b0];
        return;
    }
    // ---- GEMM role ----
    short* Wl = (short*)smem;
    {
        const uint4* src = (const uint4*)Wt;  // 2048 16B slots
        #pragma unroll
        for (int it = 0; it < 8; ++it) {
            int g = it * 256 + threadIdx.x;
            int n = g >> 5, s = g & 31;
            *(uint4*)((char*)Wl + n * 512 + (s ^ (n & 7)) * 16) = src[g];
        }
    }
    __syncthreads();

    const int wv = threadIdx.x >> 6;
    const int l  = threadIdx.x & 63;
    const int lr = l & 15;
    const int kg = l >> 4;

    const int fb = blockIdx.x - nHist;
    const int rowbase = (fb * 4 + wv) * 32;
    if (rowbase >= nRows) return;

    const int ar0 = min(rowbase + lr,      nRows - 1);
    const int ar1 = min(rowbase + 16 + lr, nRows - 1);
    const float* xp0 = x + (size_t)ar0 * IN_F + kg * 8;
    const float* xp1 = x + (size_t)ar1 * IN_F + kg * 8;

    f32x4 acc[2][4];
    #pragma unroll
    for (int m = 0; m < 2; ++m)
        #pragma unroll
        for (int n = 0; n < 4; ++n) acc[m][n] = (f32x4)0.f;

    #pragma unroll
    for (int kt = 0; kt < 8; ++kt) {
        const int K0 = kt * 32;
        float4 a0lo = *(const float4*)(xp0 + K0);
        float4 a0hi = *(const float4*)(xp0 + K0 + 4);
        float4 a1lo = *(const float4*)(xp1 + K0);
        float4 a1hi = *(const float4*)(xp1 + K0 + 4);

        short8 a0, a1;
        a0[0] = f2bf(a0lo.x); a0[1] = f2bf(a0lo.y);
        a0[2] = f2bf(a0lo.z); a0[3] = f2bf(a0lo.w);
        a0[4] = f2bf(a0hi.x); a0[5] = f2bf(a0hi.y);
        a0[6] = f2bf(a0hi.z); a0[7] = f2bf(a0hi.w);
        a1[0] = f2bf(a1lo.x); a1[1] = f2bf(a1lo.y);
        a1[2] = f2bf(a1lo.z); a1[3] = f2bf(a1lo.w);
        a1[4] = f2bf(a1hi.x); a1[5] = f2bf(a1hi.y);
        a1[6] = f2bf(a1hi.z); a1[7] = f2bf(a1hi.w);

        short8 bf[4];
        #pragma unroll
        for (int nt = 0; nt < 4; ++nt) {
            const int col = nt * 16 + lr;
            const int slot = (kt * 4 + kg) ^ (col & 7);
            bf[nt] = *(const short8*)((const char*)Wl + col * 512 + slot * 16);
        }
        #pragma unroll
        for (int nt = 0; nt < 4; ++nt) {
            acc[0][nt] = __builtin_amdgcn_mfma_f32_16x16x32_bf16(a0, bf[nt], acc[0][nt], 0, 0, 0);
            acc[1][nt] = __builtin_amdgcn_mfma_f32_16x16x32_bf16(a1, bf[nt], acc[1][nt], 0, 0, 0);
        }
    }

    #pragma unroll
    for (int m = 0; m < 2; ++m) {
        #pragma unroll
        for (int nt = 0; nt < 4; ++nt) {
            const int col = nt * 16 + lr;
            const float bb = bias[col];
            #pragma unroll
            for (int j = 0; j < 4; ++j) {
                const int r = rowbase + m * 16 + kg * 4 + j;
                if (r < nRows)
                    h[(size_t)r * OUT_F + col] = f2bf(acc[m][nt][j] + bb);
            }
        }
    }
}

// ---------------- scans ----------------
__global__ __launch_bounds__(256)
void scan1_kernel(const int* __restrict__ cnt, int* __restrict__ off,
                  int* __restrict__ part, int n) {
    __shared__ int sh[256];
    int base = blockIdx.x * 1024;
    int t = threadIdx.x;
    int v[4]; int s = 0;
    #pragma unroll
    for (int i = 0; i < 4; ++i) {
        int idx = base + t * 4 + i;
        v[i] = (idx < n) ? cnt[idx] : 0;
        s += v[i];
    }
    sh[t] = s;
    __syncthreads();
    for (int d = 1; d < 256; d <<= 1) {
        int val = (t >= d) ? sh[t - d] : 0;
        __syncthreads();
        sh[t] += val;
        __syncthreads();
    }
    if (t == 255) part[blockIdx.x] = sh[255];
    int run = (t == 0) ? 0 : sh[t - 1];
    #pragma unroll
    for (int i = 0; i < 4; ++i) {
        int idx = base + t * 4 + i;
        if (idx < n) off[idx] = run;
        run += v[i];
    }
}

// exclusive scan of up to 1024 partials, in place
__global__ __launch_bounds__(256)
void scan2_kernel(int* __restrict__ part, int nPart) {
    __shared__ int sh[256];
    int t = threadIdx.x;
    int v[4]; int s = 0;
    #pragma unroll
    for (int i = 0; i < 4; ++i) {
        int idx = t * 4 + i;
        v[i] = (idx < nPart) ? part[idx] : 0;
        s += v[i];
    }
    sh[t] = s;
    __syncthreads();
    for (int d = 1; d < 256; d <<= 1) {
        int val = (t >= d) ? sh[t - d] : 0;
        __syncthreads();
        sh[t] += val;
        __syncthreads();
    }
    int run = (t == 0) ? 0 : sh[t - 1];
    #pragma unroll
    for (int i = 0; i < 4; ++i) {
        int idx = t * 4 + i;
        if (idx < nPart) part[idx] = run;
        run += v[i];
    }
}

// ---------------- bfill: bucket-ordered pack (part base folded in) -------
__global__ __launch_bounds__(256)
void bfill_kernel(const int* __restrict__ src, const int* __restrict__ dst,
                  const float* __restrict__ w, const int* __restrict__ bases,
                  const int* __restrict__ part, int2* __restrict__ pack,
                  int nE, int NB, int nSB) {
    __shared__ int cur[MAX_NB];
    const int cb = blockIdx.x;
    for (int b0 = threadIdx.x; b0 < NB; b0 += 256) {
        int idx = b0 * nSB + cb;
        cur[b0] = bases[idx] + part[idx >> 10];
    }
    __syncthreads();
    const int base = cb * SORT_CHUNK;
    const int lim = min(nE, base + SORT_CHUNK);
    const int4* s4 = (const int4*)(src + base);
    const int4* d4 = (const int4*)(dst + base);
    const float4* w4 = (const float4*)(w + base);
    const int n4 = (lim - base) >> 2;
    for (int i = threadIdx.x; i < n4; i += 256) {
        int4 s = s4[i]; int4 d = d4[i]; float4 ww = w4[i];
        int p0 = atomicAdd(&cur[d.x >> BKT_SHIFT], 1);
        pack[p0] = make_int2(s.x | ((d.x & (BKT_NODES - 1)) << 17), __float_as_int(ww.x));
        int p1 = atomicAdd(&cur[d.y >> BKT_SHIFT], 1);
        pack[p1] = make_int2(s.y | ((d.y & (BKT_NODES - 1)) << 17), __float_as_int(ww.y));
        int p2 = atomicAdd(&cur[d.z >> BKT_SHIFT], 1);
        pack[p2] = make_int2(s.z | ((d.z & (BKT_NODES - 1)) << 17), __float_as_int(ww.z));
        int p3 = atomicAdd(&cur[d.w >> BKT_SHIFT], 1);
        pack[p3] = make_int2(s.w | ((d.w & (BKT_NODES - 1)) << 17), __float_as_int(ww.w));
    }
    for (int e = base + (n4 << 2) + threadIdx.x; e < lim; e += 256) {
        int d = dst[e];
        int p = atomicAdd(&cur[d >> BKT_SHIFT], 1);
        pack[p] = make_int2(src[e] | ((d & (BKT_NODES - 1)) << 17),
                            __float_as_int(w[e]));
    }
}

// ---------------- nsort: node-sort within bucket (4-deep ILP) ------------
__global__ __launch_bounds__(256)
void nsort_kernel(const int2* __restrict__ pack, const int* __restrict__ bases,
                  const int* __restrict__ part, int2* __restrict__ pack2,
                  int* __restrict__ off, int nRows, int nE, int NB, int nSB) {
    __shared__ int cnt[BKT_NODES];
    __shared__ int scn[BKT_NODES];
    const int b = blockIdx.x;
    const int tid = threadIdx.x;
    const int i0 = b * nSB;
    const int segStart = bases[i0] + part[i0 >> 10];
    int segEnd = nE;
    if (b + 1 < NB) {
        int i1 = (b + 1) * nSB;
        segEnd = bases[i1] + part[i1 >> 10];
    }

    if (tid < BKT_NODES) cnt[tid] = 0;
    __syncthreads();
    {
        int e = segStart + tid;
        for (; e + 768 < segEnd; e += 1024) {
            int a0 = pack[e].x, a1 = pack[e + 256].x;
            int a2 = pack[e + 512].x, a3 = pack[e + 768].x;
            atomicAdd(&cnt[(a0 >> 17) & (BKT_NODES - 1)], 1);
            atomicAdd(&cnt[(a1 >> 17) & (BKT_NODES - 1)], 1);
            atomicAdd(&cnt[(a2 >> 17) & (BKT_NODES - 1)], 1);
            atomicAdd(&cnt[(a3 >> 17) & (BKT_NODES - 1)], 1);
        }
        for (; e < segEnd; e += 256)
            atomicAdd(&cnt[(pack[e].x >> 17) & (BKT_NODES - 1)], 1);
    }
    __syncthreads();

    if (tid < BKT_NODES) scn[tid] = cnt[tid];
    __syncthreads();
    for (int d = 1; d < BKT_NODES; d <<= 1) {
        int t = 0;
        if (tid < BKT_NODES && tid >= d) t = scn[tid - d];
        __syncthreads();
        if (tid < BKT_NODES) scn[tid] += t;
        __syncthreads();
    }

    const int node0 = b * BKT_NODES;
    const int ncnt = min(BKT_NODES, nRows - node0);
    if (tid < ncnt)
        off[node0 + tid] = segStart + scn[tid] - cnt[tid];  // exclusive
    if (tid == 0 && node0 + ncnt == nRows)
        off[nRows] = segEnd;
    __syncthreads();

    if (tid < BKT_NODES) cnt[tid] = segStart + scn[tid] - cnt[tid];
    __syncthreads();
    {
        int e = segStart + tid;
        for (; e + 768 < segEnd; e += 1024) {
            int2 p0 = pack[e], p1 = pack[e + 256];
            int2 p2 = pack[e + 512], p3 = pack[e + 768];
            int q0 = atomicAdd(&cnt[(p0.x >> 17) & (BKT_NODES - 1)], 1);
            pack2[q0] = make_int2(p0.x & 0x1FFFF, p0.y);
            int q1 = atomicAdd(&cnt[(p1.x >> 17) & (BKT_NODES - 1)], 1);
            pack2[q1] = make_int2(p1.x & 0x1FFFF, p1.y);
            int q2 = atomicAdd(&cnt[(p2.x >> 17) & (BKT_NODES - 1)], 1);
            pack2[q2] = make_int2(p2.x & 0x1FFFF, p2.y);
            int q3 = atomicAdd(&cnt[(p3.x >> 17) & (BKT_NODES - 1)], 1);
            pack2[q3] = make_int2(p3.x & 0x1FFFF, p3.y);
        }
        for (; e < segEnd; e += 256) {
            int2 p = pack[e];
            int q = atomicAdd(&cnt[(p.x >> 17) & (BKT_NODES - 1)], 1);
            pack2[q] = make_int2(p.x & 0x1FFFF, p.y);
        }
    }
}

// ---------------- ngather: one wave per node ----------------
__global__ __launch_bounds__(256)
void ngather_kernel(const short* __restrict__ h, const int* __restrict__ off,
                    const int2* __restrict__ pack2, float* __restrict__ out,
                    int nNodes) {
    int wid = (blockIdx.x * 256 + threadIdx.x) >> 6;
    int lane = threadIdx.x & 63;
    if (wid >= nNodes) return;
    int e = off[wid], end = off[wid + 1];
    const ushort* hu = (const ushort*)h;
    float acc = 0.f;
    for (; e + 8 <= end; e += 8) {
        int2 pk[8];
        #pragma unroll
        for (int i = 0; i < 8; ++i) pk[i] = pack2[e + i];
        float hv[8];
        #pragma unroll
        for (int i = 0; i < 8; ++i)
            hv[i] = bf2f((short)hu[(size_t)pk[i].x * OUT_F + lane]);
        #pragma unroll
        for (int i = 0; i < 8; ++i)
            acc = fmaf(__int_as_float(pk[i].y), hv[i], acc);
    }
    for (; e + 4 <= end; e += 4) {
        int2 pk[4];
        #pragma unroll
        for (int i = 0; i < 4; ++i) pk[i] = pack2[e + i];
        #pragma unroll
        for (int i = 0; i < 4; ++i)
            acc = fmaf(__int_as_float(pk[i].y),
                       bf2f((short)hu[(size_t)pk[i].x * OUT_F + lane]), acc);
    }
    for (; e < end; ++e) {
        int2 p = pack2[e];
        acc = fmaf(__int_as_float(p.y),
                   bf2f((short)hu[(size_t)p.x * OUT_F + lane]), acc);
    }
    out[(size_t)wid * OUT_F + lane] = acc;
}

// ---------------- fallback (atomic) scatter ----------------
__global__ __launch_bounds__(256)
void scatter_kernel(const short* __restrict__ h, const int* __restrict__ src,
                    const int* __restrict__ dst, const float* __restrict__ w,
                    float* __restrict__ out, int nE) {
    int t = blockIdx.x * 256 + threadIdx.x;
    int c = t & 15;
    int stride = (gridDim.x * 256) >> 4;
    for (int e = t >> 4; e < nE; e += stride) {
        int s = src[e];
        int d = dst[e];
        float ww = w[e];
        float* op = out + (size_t)d * OUT_F + c * 4;
        const short* hp = h + (size_t)s * OUT_F + c * 4;
        unsafeAtomicAdd(op + 0, ww * bf2f(hp[0]));
        unsafeAtomicAdd(op + 1, ww * bf2f(hp[1]));
        unsafeAtomicAdd(op + 2, ww * bf2f(hp[2]));
        unsafeAtomicAdd(op + 3, ww * bf2f(hp[3]));
    }
}

static inline size_t align256(size_t x) { return (x + 255) & ~(size_t)255; }

extern "C" void kernel_launch(void* const* d_in, const int* in_sizes, int n_in,
                              void* d_out, int out_size, void* d_ws, size_t ws_size,
                              hipStream_t stream) {
    const float* x    = (const float*)d_in[0];
    const int*   esrc = (const int*)d_in[1];
    const int*   edst = (const int*)d_in[2];
    const float* ew   = (const float*)d_in[3];
    const float* W    = (const float*)d_in[4];
    const float* b    = (const float*)d_in[5];

    int nRows = in_sizes[0] / IN_F;   // 100000
    int nE    = in_sizes[1];          // 1600000

    int NB  = (nRows + BKT_NODES - 1) / BKT_NODES;   // 782
    int nSB = (nE + SORT_CHUNK - 1) / SORT_CHUNK;    // 391
    int nCnt = NB * nSB;                             // 305762
    int nPart = (nCnt + 1023) / 1024;                // 299

    // workspace layout
    char* p = (char*)d_ws;
    size_t hB    = align256((size_t)nRows * OUT_F * sizeof(short));
    size_t wtB   = align256((size_t)IN_F * OUT_F * sizeof(short));
    size_t cntB  = align256((size_t)nCnt * sizeof(int));
    size_t basB  = align256((size_t)nCnt * sizeof(int));
    size_t partB = align256((size_t)nPart * sizeof(int));
    size_t packB = align256((size_t)nE * sizeof(int2));
    size_t offB  = align256((size_t)(nRows + 1) * sizeof(int));
    size_t need  = hB + wtB + cntB + basB + partB + 2 * packB + offB;

    short* h      = (short*)p;  p += hB;
    short* Wt     = (short*)p;  p += wtB;
    int*   counts = (int*)p;    p += cntB;
    int*   bases  = (int*)p;    p += basB;
    int*   part   = (int*)p;    p += partB;
    int2*  pack   = (int2*)p;   p += packB;
    int2*  pack2  = (int2*)p;   p += packB;
    int*   off    = (int*)p;

    float* out = (float*)d_out;

    bool ok = (ws_size >= need) && (NB <= MAX_NB) && (nPart <= 1024) &&
              (nRows < (1 << 17));
    int nHist = ok ? nSB : 0;
    int fcBlocks = (nRows + 127) / 128;   // 782

    prep_w_kernel<<<(IN_F * OUT_F + 255) / 256, 256, 0, stream>>>(W, Wt);
    fc_bhist_kernel<<<nHist + fcBlocks, 256, 0, stream>>>(
        x, Wt, b, h, edst, counts, nRows, nE, NB, nSB, nHist);

    if (ok) {
        scan1_kernel<<<nPart, 256, 0, stream>>>(counts, bases, part, nCnt);
        scan2_kernel<<<1, 256, 0, stream>>>(part, nPart);
        bfill_kernel<<<nSB, 256, 0, stream>>>(esrc, edst, ew, bases, part,
                                              pack, nE, NB, nSB);
        nsort_kernel<<<NB, 256, 0, stream>>>(pack, bases, part, pack2, off,
                                             nRows, nE, NB, nSB);
        int gBlocks = (nRows * 64 + 255) / 256;
        ngather_kernel<<<gBlocks, 256, 0, stream>>>(h, off, pack2, out, nRows);
    } else {
        hipMemsetAsync(out, 0, (size_t)out_size * sizeof(float), stream);
        scatter_kernel<<<4096, 256, 0, stream>>>(h, esrc, edst, ew, out, nE);
    }
}